// Round 5
// baseline (232.773 us; speedup 1.0000x reference)
//
#include <hip/hip_runtime.h>
#include <math.h>

#define S_LEN 262144
#define N 128
#define TPB 256
#define GRID 768
#define NWAVES (GRID * 4)          // 3072 waves
#define ITEMS (S_LEN / 16 * 2)     // strip(16 rows) x col-half = 32768 items

typedef __attribute__((ext_vector_type(8))) short bf16x8;
typedef __attribute__((ext_vector_type(4))) float f32x4;

__device__ __forceinline__ unsigned short f2bf(float x) {
    unsigned b = __float_as_uint(x);
    b = (b + 0x7FFF + ((b >> 16) & 1)) >> 16;   // RNE to bf16
    return (unsigned short)b;
}
__device__ __forceinline__ float bf2f(unsigned short u) {
    return __uint_as_float((unsigned)u << 16);
}
// low16 = bf16(x), high16 = bf16(y) (round-half-up): 2 adds + 1 perm
__device__ __forceinline__ unsigned pack2bf(float x, float y) {
    return __builtin_amdgcn_perm(__float_as_uint(y) + 0x8000u,
                                 __float_as_uint(x) + 0x8000u, 0x07060302u);
}
__device__ __forceinline__ float wave_reduce(float v) {
    #pragma unroll
    for (int off = 32; off > 0; off >>= 1) v += __shfl_down(v, off, 64);
    return v;
}
// intra-wave LDS ordering fence: drain DS queue + stop compiler reordering.
// Does NOT touch vmcnt (global loads stay in flight) and is NOT a barrier.
__device__ __forceinline__ void lds_fence() {
    asm volatile("s_waitcnt lgkmcnt(0)" ::: "memory");
}

// M = W_K^T @ W_Q (128x128) fp32; emit bf16 in MFMA-B-fragment order:
//   frag[((kk*8 + ct)*64 + lane)*8 + j] = M[kk*32 + (lane>>4)*8 + j][ct*16 + (lane&15)]
// l1 partials (sum sigmoid(M) per block) -> wsP[block]; out[0] zeroed here so
// main_kernel's atomics land on a clean slate (kernel-boundary ordering).
// Full unroll + 4 accumulator chains keeps ~32 cold-HBM loads in flight.
__global__ void mk_kernel(const float* __restrict__ WQ, const float* __restrict__ WK,
                          unsigned short* __restrict__ fragB, float* __restrict__ wsP,
                          float* __restrict__ out) {
    const int i = blockIdx.x;   // M row (k of main GEMM) -- uniform => scalar loads
    const int j = threadIdx.x;  // M col
    float a0 = 0.f, a1 = 0.f, a2 = 0.f, a3 = 0.f;
    #pragma unroll
    for (int r = 0; r < N; r += 4) {
        a0 = fmaf(WK[(r + 0) * N + i], WQ[(r + 0) * N + j], a0);
        a1 = fmaf(WK[(r + 1) * N + i], WQ[(r + 1) * N + j], a1);
        a2 = fmaf(WK[(r + 2) * N + i], WQ[(r + 2) * N + j], a2);
        a3 = fmaf(WK[(r + 3) * N + i], WQ[(r + 3) * N + j], a3);
    }
    const float acc = (a0 + a1) + (a2 + a3);

    const int kk = i >> 5, q = (i >> 3) & 3, jj = i & 7;
    const int ct = j >> 4, n15 = j & 15;
    fragB[((kk * 8 + ct) * 64 + (q * 16 + n15)) * 8 + jj] = f2bf(acc);

    float sg = fabsf(1.0f / (1.0f + __expf(-acc)));
    float ws = wave_reduce(sg);
    __shared__ float red[2];
    if ((j & 63) == 0) red[j >> 6] = ws;
    __syncthreads();
    if (j == 0) wsP[i] = red[0] + red[1];
    if (i == 0 && j == 0) out[0] = 0.f;
}

// Wave-autonomous: each wave owns (strip of 16 rows) x (64 cols). The duplicate
// strip read by the paired col-half wave is an L2/L3 hit, so HBM fetch ~134 MB.
// 2-DEEP register pipeline: two NAMED load-register sets (rA/xA, rB/xB) with the
// loop manually unrolled x2 (static indexing only -- runtime-indexed sets go to
// scratch). A-body packs rA -> LDS buf0 and immediately re-issues rA for
// item+2*NWAVES; B-body likewise with buf1. Issue->consume distance ~= 2 full
// bodies, so the pack's vmcnt wait finds data already landed (the 1-deep version
// stalled 500-1200 cy per iteration at the top of pack).
__global__ __launch_bounds__(TPB, 3) void main_kernel(
    const float* __restrict__ In, const unsigned short* __restrict__ fragB,
    const float* __restrict__ wsP, float* __restrict__ out, float inv_denom) {
    __shared__ unsigned short sA[4][2][17][132];  // per-wave strip x2: 16 rows + boundary
    __shared__ float sRed[4];

    const int tid = threadIdx.x;
    const int w = tid >> 6, lane = tid & 63;
    const int q = lane >> 4, n15 = lane & 15;
    const int gid = blockIdx.x * 4 + w;          // global wave id
    const int half = gid & 1;                    // col half (item stride is even)

    float lsum = 0.f;
    float4 rA[8], rB[8];
    float2 xA, xB;

    auto issue = [&](int item, float4 (&r)[8], float2& x) {
        const long r0 = (long)(item >> 1) * 16;
        const float* base = In + r0 * N;
        #pragma unroll
        for (int j = 0; j < 8; ++j)              // 8 x 1KB chunks: rows 2j, 2j+1
            r[j] = *(const float4*)(base + j * 256 + lane * 4);
        long rX = r0 + 16; if (rX > S_LEN - 1) rX = S_LEN - 1;
        x = *(const float2*)&In[rX * N + lane * 2];   // boundary row, all 64 lanes
    };

    // both pipeline stages' HBM loads in flight BEFORE touching fragB: the
    // fragment loads (L2-resident, mk just wrote them) hide under HBM latency.
    // gid+NWAVES <= 3071+3072 < ITEMS, so the B prefetch needs no guard.
    issue(gid, rA, xA);
    issue(gid + NWAVES, rB, xB);

    // B fragments for this wave's 64 cols (ct = half*4 + c4), constant all kernel
    bf16x8 bF[4][4];
    #pragma unroll
    for (int c4 = 0; c4 < 4; ++c4)
        #pragma unroll
        for (int kk = 0; kk < 4; ++kk)
            bF[c4][kk] = *(const bf16x8*)&fragB[((kk * 8 + (half * 4 + c4)) * 64 + lane) * 8];

    bf16x8 bOne;   // all-ones B: rowsum via MFMA, C/D layout matches epilogue
    #pragma unroll
    for (int e = 0; e < 8; ++e) bOne[e] = (short)0x3F80;

    // block 0, wave 0: finalize l1 from mk's 128 per-block partials (single writer)
    if (blockIdx.x == 0 && w == 0) {
        float p = wsP[lane] + wsP[lane + 64];
        float s = wave_reduce(p);
        if (lane == 0) out[1] = s;
    }

    auto body = [&](int item, float4 (&r)[8], float2& x, unsigned short (*my)[132]) {
        // pack fp32 regs -> bf16 LDS strip (compiler inserts vmcnt waits for r/x;
        // these loads were issued TWO bodies ago -- already landed, no stall)
        #pragma unroll
        for (int j = 0; j < 8; ++j) {
            const int row = 2 * j + (lane >> 5);
            const int c = lane & 31;
            *(unsigned int*)&my[row][c * 4] = pack2bf(r[j].x, r[j].y);
            *(unsigned int*)&my[row][c * 4 + 2] = pack2bf(r[j].z, r[j].w);
        }
        *(unsigned int*)&my[16][lane * 2] = pack2bf(x.x, x.y);

        // refill this register set: loads for item + 2*NWAVES go in flight now
        const int nn = item + 2 * NWAVES;
        if (nn < ITEMS) issue(nn, r, x);

        lds_fence();   // pack visible to all lanes of this wave before fragment reads

        // MFMA: z (4 col-tiles) + rowsum, K=128
        f32x4 acc[4], aRS;
        aRS = (f32x4){0.f, 0.f, 0.f, 0.f};
        #pragma unroll
        for (int c4 = 0; c4 < 4; ++c4) acc[c4] = (f32x4){0.f, 0.f, 0.f, 0.f};
        #pragma unroll
        for (int kk = 0; kk < 4; ++kk) {
            bf16x8 a = *(const bf16x8*)&my[n15][kk * 32 + q * 8];  // A[m=n15][k=q*8+j]
            aRS = __builtin_amdgcn_mfma_f32_16x16x32_bf16(a, bOne, aRS, 0, 0, 0);
            #pragma unroll
            for (int c4 = 0; c4 < 4; ++c4)
                acc[c4] = __builtin_amdgcn_mfma_f32_16x16x32_bf16(a, bF[c4][kk], acc[c4], 0, 0, 0);
        }

        // epilogue: C/D row = q*4+reg, col = n15 (per 16-tile); reads THIS buf,
        // the other body packs into the other buf -- no tail fence needed.
        const long r0 = (long)(item >> 1) * 16;
        #pragma unroll
        for (int reg = 0; reg < 4; ++reg) {
            const int row = q * 4 + reg;
            const float rs = aRS[reg];
            const long s = r0 + row;
            const bool has = (s < S_LEN - 1);
            #pragma unroll
            for (int c4 = 0; c4 < 4; ++c4) {
                const float z = acc[c4][reg];
                const float sp = fmaxf(z, 0.f) + __logf(1.0f + __expf(-fabsf(z)));
                const float o = sp * rs;
                if (has) {
                    const int col = half * 64 + c4 * 16 + n15;
                    const float d = o - bf2f(my[row + 1][col]);
                    lsum = fmaf(d, d, lsum);
                }
            }
        }
    };

    int item = gid;
    while (item < ITEMS) {
        body(item, rA, xA, sA[w][0]);          // A body: buf0
        item += NWAVES;
        if (item >= ITEMS) break;
        body(item, rB, xB, sA[w][1]);          // B body: buf1
        item += NWAVES;
    }

    const float wsum = wave_reduce(lsum);
    if ((tid & 63) == 0) sRed[w] = wsum;
    __syncthreads();
    if (tid == 0) {
        float t = 0.f;
        #pragma unroll
        for (int w2 = 0; w2 < 4; ++w2) t += sRed[w2];
        atomicAdd(&out[0], t * inv_denom);
    }
}

extern "C" void kernel_launch(void* const* d_in, const int* in_sizes, int n_in,
                              void* d_out, int out_size, void* d_ws, size_t ws_size,
                              hipStream_t stream) {
    const float* In = (const float*)d_in[0];
    const float* WQ = (const float*)d_in[1];
    const float* WK = (const float*)d_in[2];
    float* out = (float*)d_out;
    unsigned short* fragB = (unsigned short*)d_ws;          // 32 KB
    float* wsP = (float*)((char*)d_ws + 32 * 1024);         // 128 floats: l1 partials

    mk_kernel<<<128, 128, 0, stream>>>(WQ, WK, fragB, wsP, out);
    const float inv = (float)(1.0 / ((double)(S_LEN - 1) * (double)N));
    main_kernel<<<GRID, TPB, 0, stream>>>(In, fragB, wsP, out, inv);
}

// Round 6
// 204.309 us; speedup vs baseline: 1.1393x; 1.1393x over previous
//
#include <hip/hip_runtime.h>
#include <math.h>

#define S_LEN 262144
#define N 128
#define TPB 256
#define GRID 768
#define NWAVES (GRID * 4)          // 3072 waves
#define ITEMS (S_LEN / 16 * 2)     // strip(16 rows) x col-half = 32768 items

typedef __attribute__((ext_vector_type(8))) short bf16x8;
typedef __attribute__((ext_vector_type(4))) float f32x4;

__device__ __forceinline__ unsigned short f2bf(float x) {
    unsigned b = __float_as_uint(x);
    b = (b + 0x7FFF + ((b >> 16) & 1)) >> 16;   // RNE to bf16
    return (unsigned short)b;
}
__device__ __forceinline__ float bf2f(unsigned short u) {
    return __uint_as_float((unsigned)u << 16);
}
// low16 = bf16(x), high16 = bf16(y) (round-half-up): 2 adds + 1 perm
__device__ __forceinline__ unsigned pack2bf(float x, float y) {
    return __builtin_amdgcn_perm(__float_as_uint(y) + 0x8000u,
                                 __float_as_uint(x) + 0x8000u, 0x07060302u);
}
__device__ __forceinline__ float wave_reduce(float v) {
    #pragma unroll
    for (int off = 32; off > 0; off >>= 1) v += __shfl_down(v, off, 64);
    return v;
}
// intra-wave LDS ordering fence: drain DS queue + stop compiler reordering.
// Does NOT touch vmcnt (global loads stay in flight) and is NOT a barrier.
__device__ __forceinline__ void lds_fence() {
    asm volatile("s_waitcnt lgkmcnt(0)" ::: "memory");
}

// M = W_K^T @ W_Q (128x128) fp32; emit bf16 in MFMA-B-fragment order:
//   frag[((kk*8 + ct)*64 + lane)*8 + j] = M[kk*32 + (lane>>4)*8 + j][ct*16 + (lane&15)]
// l1 partials (sum sigmoid(M) per block) -> wsP[block]; out[0] zeroed here so
// main_kernel's atomics land on a clean slate (kernel-boundary ordering).
__global__ void mk_kernel(const float* __restrict__ WQ, const float* __restrict__ WK,
                          unsigned short* __restrict__ fragB, float* __restrict__ wsP,
                          float* __restrict__ out) {
    const int i = blockIdx.x;   // M row (k of main GEMM) -- uniform => scalar loads
    const int j = threadIdx.x;  // M col
    float a0 = 0.f, a1 = 0.f, a2 = 0.f, a3 = 0.f;
    #pragma unroll
    for (int r = 0; r < N; r += 4) {
        a0 = fmaf(WK[(r + 0) * N + i], WQ[(r + 0) * N + j], a0);
        a1 = fmaf(WK[(r + 1) * N + i], WQ[(r + 1) * N + j], a1);
        a2 = fmaf(WK[(r + 2) * N + i], WQ[(r + 2) * N + j], a2);
        a3 = fmaf(WK[(r + 3) * N + i], WQ[(r + 3) * N + j], a3);
    }
    const float acc = (a0 + a1) + (a2 + a3);

    const int kk = i >> 5, q = (i >> 3) & 3, jj = i & 7;
    const int ct = j >> 4, n15 = j & 15;
    fragB[((kk * 8 + ct) * 64 + (q * 16 + n15)) * 8 + jj] = f2bf(acc);

    float sg = fabsf(1.0f / (1.0f + __expf(-acc)));
    float ws = wave_reduce(sg);
    __shared__ float red[2];
    if ((j & 63) == 0) red[j >> 6] = ws;
    __syncthreads();
    if (j == 0) wsP[i] = red[0] + red[1];
    if (i == 0 && j == 0) out[0] = 0.f;
}

// ---- codegen-safe macros: arrays only ever accessed by name with static
// indices inside unrolled loops (never passed by reference / address-taken,
// which demoted them to scratch in the previous revision: VGPR=84 + 25MB
// scratch writes). ----
#define ISSUE(RS, XS, it) do {                                                  \
    const long _r0 = (long)((it) >> 1) * 16;                                    \
    const float* _base = In + _r0 * N;                                          \
    _Pragma("unroll")                                                           \
    for (int _j = 0; _j < 8; ++_j)                                              \
        RS[_j] = *(const float4*)(_base + _j * 256 + lane * 4);                 \
    long _rX = _r0 + 16; if (_rX > S_LEN - 1) _rX = S_LEN - 1;                  \
    XS = *(const float2*)&In[_rX * N + lane * 2];                               \
} while (0)

#define BODY(RS, XS, MY, it) do {                                               \
    /* pack fp32 regs -> bf16 LDS strip (loads landed ~2 bodies ago) */         \
    _Pragma("unroll")                                                           \
    for (int _j = 0; _j < 8; ++_j) {                                            \
        const int _row = 2 * _j + (lane >> 5);                                  \
        const int _c = lane & 31;                                               \
        *(unsigned int*)&MY[_row][_c * 4]     = pack2bf(RS[_j].x, RS[_j].y);    \
        *(unsigned int*)&MY[_row][_c * 4 + 2] = pack2bf(RS[_j].z, RS[_j].w);    \
    }                                                                           \
    *(unsigned int*)&MY[16][lane * 2] = pack2bf(XS.x, XS.y);                    \
    /* refill this register set: item + 2*NWAVES goes in flight now */          \
    const int _nn = (it) + 2 * NWAVES;                                          \
    if (_nn < ITEMS) ISSUE(RS, XS, _nn);                                        \
    lds_fence();                                                                \
    f32x4 _acc[4], _aRS = (f32x4){0.f, 0.f, 0.f, 0.f};                          \
    _Pragma("unroll")                                                           \
    for (int _c4 = 0; _c4 < 4; ++_c4) _acc[_c4] = (f32x4){0.f, 0.f, 0.f, 0.f}; \
    _Pragma("unroll")                                                           \
    for (int _kk = 0; _kk < 4; ++_kk) {                                         \
        bf16x8 _a = *(const bf16x8*)&MY[n15][_kk * 32 + q * 8];                 \
        _aRS = __builtin_amdgcn_mfma_f32_16x16x32_bf16(_a, bOne, _aRS, 0, 0, 0);\
        _Pragma("unroll")                                                       \
        for (int _c4 = 0; _c4 < 4; ++_c4)                                       \
            _acc[_c4] = __builtin_amdgcn_mfma_f32_16x16x32_bf16(                \
                _a, bF[_c4][_kk], _acc[_c4], 0, 0, 0);                          \
    }                                                                           \
    const long _s0 = (long)((it) >> 1) * 16;                                    \
    _Pragma("unroll")                                                           \
    for (int _reg = 0; _reg < 4; ++_reg) {                                      \
        const int _row = q * 4 + _reg;                                          \
        const float _rs = _aRS[_reg];                                           \
        const bool _has = (_s0 + _row < S_LEN - 1);                             \
        _Pragma("unroll")                                                       \
        for (int _c4 = 0; _c4 < 4; ++_c4) {                                     \
            const float _z = _acc[_c4][_reg];                                   \
            const float _sp = fmaxf(_z, 0.f) + __logf(1.0f + __expf(-fabsf(_z)));\
            const float _o = _sp * _rs;                                         \
            if (_has) {                                                         \
                const int _col = half * 64 + _c4 * 16 + n15;                    \
                const float _d = _o - bf2f(MY[_row + 1][_col]);                 \
                lsum = fmaf(_d, _d, lsum);                                      \
            }                                                                   \
        }                                                                       \
    }                                                                           \
} while (0)

// Wave-autonomous, 2-DEEP register pipeline: named sets rA/xA (LDS buf0) and
// rB/xB (buf1), loop unrolled x2 via macros. Issue->consume distance ~= 2 full
// bodies (~1200+ cy) >= loaded HBM latency, so pack's vmcnt wait finds data
// landed. __launch_bounds__(256,2): VGPR cap 256 so rA+rB+bF (~180 live) fit
// with NO spills (at (256,3) the 170-reg cap collapsed regalloc to 84+scratch).
__global__ __launch_bounds__(TPB, 2) void main_kernel(
    const float* __restrict__ In, const unsigned short* __restrict__ fragB,
    const float* __restrict__ wsP, float* __restrict__ out, float inv_denom) {
    __shared__ unsigned short sA[4][2][17][132];  // per-wave strip x2: 16 rows + boundary
    __shared__ float sRed[4];

    const int tid = threadIdx.x;
    const int w = tid >> 6, lane = tid & 63;
    const int q = lane >> 4, n15 = lane & 15;
    const int gid = blockIdx.x * 4 + w;          // global wave id
    const int half = gid & 1;                    // col half (item stride is even)

    float lsum = 0.f;
    float4 rA[8], rB[8];
    float2 xA, xB;

    // both pipeline stages' HBM loads in flight BEFORE touching fragB: the
    // fragment loads (L2-resident, mk just wrote them) hide under HBM latency.
    // gid+NWAVES <= 3071+3072 < ITEMS, so the B prefetch needs no guard.
    ISSUE(rA, xA, gid);
    ISSUE(rB, xB, gid + NWAVES);

    // B fragments for this wave's 64 cols (ct = half*4 + c4), constant all kernel
    bf16x8 bF[4][4];
    #pragma unroll
    for (int c4 = 0; c4 < 4; ++c4)
        #pragma unroll
        for (int kk = 0; kk < 4; ++kk)
            bF[c4][kk] = *(const bf16x8*)&fragB[((kk * 8 + (half * 4 + c4)) * 64 + lane) * 8];

    bf16x8 bOne;   // all-ones B: rowsum via MFMA, C/D layout matches epilogue
    #pragma unroll
    for (int e = 0; e < 8; ++e) bOne[e] = (short)0x3F80;

    // block 0, wave 0: finalize l1 from mk's 128 per-block partials (single writer)
    if (blockIdx.x == 0 && w == 0) {
        float p = wsP[lane] + wsP[lane + 64];
        float s = wave_reduce(p);
        if (lane == 0) out[1] = s;
    }

    unsigned short (*my0)[132] = sA[w][0];
    unsigned short (*my1)[132] = sA[w][1];

    int item = gid;
    while (item < ITEMS) {
        BODY(rA, xA, my0, item);               // A body: buf0
        item += NWAVES;
        if (item >= ITEMS) break;
        BODY(rB, xB, my1, item);               // B body: buf1
        item += NWAVES;
    }

    const float wsum = wave_reduce(lsum);
    if ((tid & 63) == 0) sRed[w] = wsum;
    __syncthreads();
    if (tid == 0) {
        float t = 0.f;
        #pragma unroll
        for (int w2 = 0; w2 < 4; ++w2) t += sRed[w2];
        atomicAdd(&out[0], t * inv_denom);
    }
}

extern "C" void kernel_launch(void* const* d_in, const int* in_sizes, int n_in,
                              void* d_out, int out_size, void* d_ws, size_t ws_size,
                              hipStream_t stream) {
    const float* In = (const float*)d_in[0];
    const float* WQ = (const float*)d_in[1];
    const float* WK = (const float*)d_in[2];
    float* out = (float*)d_out;
    unsigned short* fragB = (unsigned short*)d_ws;          // 32 KB
    float* wsP = (float*)((char*)d_ws + 32 * 1024);         // 128 floats: l1 partials

    mk_kernel<<<128, 128, 0, stream>>>(WQ, WK, fragB, wsP, out);
    const float inv = (float)(1.0 / ((double)(S_LEN - 1) * (double)N));
    main_kernel<<<GRID, TPB, 0, stream>>>(In, fragB, wsP, out, inv);
}

// Round 7
// 204.220 us; speedup vs baseline: 1.1398x; 1.0004x over previous
//
#include <hip/hip_runtime.h>
#include <math.h>

#define S_LEN 262144
#define N 128
#define TPB 256
#define GRID 768
#define NWAVES (GRID * 4)          // 3072 waves
#define ITEMS (S_LEN / 16 * 2)     // strip(16 rows) x col-half = 32768 items

typedef __attribute__((ext_vector_type(8))) short bf16x8;
typedef __attribute__((ext_vector_type(4))) float f32x4;
typedef __attribute__((ext_vector_type(4))) unsigned u32x4;

__device__ __forceinline__ unsigned short f2bf(float x) {
    unsigned b = __float_as_uint(x);
    b = (b + 0x7FFF + ((b >> 16) & 1)) >> 16;   // RNE to bf16
    return (unsigned short)b;
}
__device__ __forceinline__ float bf2f(unsigned short u) {
    return __uint_as_float((unsigned)u << 16);
}
// low16 = bf16(x), high16 = bf16(y) (round-half-up): 2 adds + 1 perm
__device__ __forceinline__ unsigned pack2bf(float x, float y) {
    return __builtin_amdgcn_perm(__float_as_uint(y) + 0x8000u,
                                 __float_as_uint(x) + 0x8000u, 0x07060302u);
}
__device__ __forceinline__ float wave_reduce(float v) {
    #pragma unroll
    for (int off = 32; off > 0; off >>= 1) v += __shfl_down(v, off, 64);
    return v;
}
// intra-wave LDS ordering fence: drain DS queue + stop compiler reordering.
// Does NOT touch vmcnt (global loads stay in flight) and is NOT a barrier.
__device__ __forceinline__ void lds_fence() {
    asm volatile("s_waitcnt lgkmcnt(0)" ::: "memory");
}

// M = W_K^T @ W_Q (128x128) fp32; emit bf16 in MFMA-B-fragment order:
//   frag[((kk*8 + ct)*64 + lane)*8 + j] = M[kk*32 + (lane>>4)*8 + j][ct*16 + (lane&15)]
// l1 partials (sum sigmoid(M) per block) -> wsP[block]; out[0] zeroed here so
// main_kernel's atomics land on a clean slate (kernel-boundary ordering).
__global__ void mk_kernel(const float* __restrict__ WQ, const float* __restrict__ WK,
                          unsigned short* __restrict__ fragB, float* __restrict__ wsP,
                          float* __restrict__ out) {
    const int i = blockIdx.x;   // M row (k of main GEMM) -- uniform => scalar loads
    const int j = threadIdx.x;  // M col
    float a0 = 0.f, a1 = 0.f, a2 = 0.f, a3 = 0.f;
    #pragma unroll
    for (int r = 0; r < N; r += 4) {
        a0 = fmaf(WK[(r + 0) * N + i], WQ[(r + 0) * N + j], a0);
        a1 = fmaf(WK[(r + 1) * N + i], WQ[(r + 1) * N + j], a1);
        a2 = fmaf(WK[(r + 2) * N + i], WQ[(r + 2) * N + j], a2);
        a3 = fmaf(WK[(r + 3) * N + i], WQ[(r + 3) * N + j], a3);
    }
    const float acc = (a0 + a1) + (a2 + a3);

    const int kk = i >> 5, q = (i >> 3) & 3, jj = i & 7;
    const int ct = j >> 4, n15 = j & 15;
    fragB[((kk * 8 + ct) * 64 + (q * 16 + n15)) * 8 + jj] = f2bf(acc);

    float sg = fabsf(1.0f / (1.0f + __expf(-acc)));
    float ws = wave_reduce(sg);
    __shared__ float red[2];
    if ((j & 63) == 0) red[j >> 6] = ws;
    __syncthreads();
    if (j == 0) wsP[i] = red[0] + red[1];
    if (i == 0 && j == 0) out[0] = 0.f;
}

// Wave-autonomous, TRANSPOSED-LOAD variant: each lane loads its MFMA A-fragment
// data straight from global (row n15, col-chunks kk*32+q*8), converts to bf16 in
// registers, and feeds MFMA with NO LDS on the critical path (the old
// load->pack->lgkm-drain->ds_read->MFMA serial chain, present in every prior
// variant, is gone). LDS keeps only an epilogue copy of the strip (4 x
// ds_write_b128 + 1 b32), whose drain overlaps the MFMA block.
__global__ __launch_bounds__(TPB, 3) void main_kernel(
    const float* __restrict__ In, const unsigned short* __restrict__ fragB,
    const float* __restrict__ wsP, float* __restrict__ out, float inv_denom) {
    __shared__ unsigned short sA[4][17][136];   // per-wave strip (136: 16B-aligned rows)
    __shared__ float sRed[4];

    const int tid = threadIdx.x;
    const int w = tid >> 6, lane = tid & 63;
    const int q = lane >> 4, n15 = lane & 15;
    const int gid = blockIdx.x * 4 + w;          // global wave id
    const int half = gid & 1;                    // col half (item stride is even)

    unsigned short (*my)[136] = sA[w];
    float lsum = 0.f;
    float4 r[8];                                 // r[2kk+h]: In[r0+n15][kk*32+q*8+4h ..]
    float2 x;
    const int eoff = n15 * N + q * 8;            // lane's transposed element offset

#define ISSUE(it) do {                                                          \
    const long _r0 = (long)((it) >> 1) * 16;                                    \
    const float* _b = In + _r0 * N + eoff;                                      \
    _Pragma("unroll")                                                           \
    for (int _kk = 0; _kk < 4; ++_kk) {                                         \
        r[2 * _kk]     = *(const float4*)(_b + _kk * 32);                       \
        r[2 * _kk + 1] = *(const float4*)(_b + _kk * 32 + 4);                   \
    }                                                                           \
    long _rX = _r0 + 16; if (_rX > S_LEN - 1) _rX = S_LEN - 1;                  \
    x = *(const float2*)&In[_rX * N + lane * 2];                                \
} while (0)

    // first item's HBM loads in flight BEFORE touching fragB: the fragment
    // loads (L2-resident, mk just wrote them) hide under HBM latency
    ISSUE(gid);

    // B fragments for this wave's 64 cols (ct = half*4 + c4), constant all kernel
    bf16x8 bF[4][4];
    #pragma unroll
    for (int c4 = 0; c4 < 4; ++c4)
        #pragma unroll
        for (int kk = 0; kk < 4; ++kk)
            bF[c4][kk] = *(const bf16x8*)&fragB[((kk * 8 + (half * 4 + c4)) * 64 + lane) * 8];

    bf16x8 bOne;   // all-ones B: rowsum via MFMA, C/D layout matches epilogue
    #pragma unroll
    for (int e = 0; e < 8; ++e) bOne[e] = (short)0x3F80;

    // block 0, wave 0: finalize l1 from mk's 128 per-block partials (single writer)
    if (blockIdx.x == 0 && w == 0) {
        float p = wsP[lane] + wsP[lane + 64];
        float s = wave_reduce(p);
        if (lane == 0) out[1] = s;
    }

// fp32 -> bf16 A-fragment for one kk (vmcnt waits auto-inserted by compiler)
#define BUILD(A, KK) do {                                                       \
    u32x4 _u;                                                                   \
    _u.x = pack2bf(r[2 * KK].x,     r[2 * KK].y);                               \
    _u.y = pack2bf(r[2 * KK].z,     r[2 * KK].w);                               \
    _u.z = pack2bf(r[2 * KK + 1].x, r[2 * KK + 1].y);                           \
    _u.w = pack2bf(r[2 * KK + 1].z, r[2 * KK + 1].w);                           \
    A = __builtin_bit_cast(bf16x8, _u);                                         \
} while (0)

#define KSTEP(A, KK) do {                                                       \
    aRS = __builtin_amdgcn_mfma_f32_16x16x32_bf16(A, bOne, aRS, 0, 0, 0);       \
    _Pragma("unroll")                                                           \
    for (int _c4 = 0; _c4 < 4; ++_c4)                                           \
        acc[_c4] = __builtin_amdgcn_mfma_f32_16x16x32_bf16(A, bF[_c4][KK],      \
                                                           acc[_c4], 0, 0, 0); \
} while (0)

    int item = gid;
    while (item < ITEMS) {
        const int next = item + NWAVES;

        // convert loaded fp32 -> bf16 fragments in registers
        bf16x8 a0, a1, a2, a3;
        BUILD(a0, 0); BUILD(a1, 1); BUILD(a2, 2); BUILD(a3, 3);
        const unsigned xw = pack2bf(x.x, x.y);

        // stage the epilogue copy of the strip: 4 x ds_write_b128 + 1 b32
        // (rows 16B-aligned via [136] stride; drains during the MFMA block)
        *(bf16x8*)&my[n15][q * 8]      = a0;
        *(bf16x8*)&my[n15][32 + q * 8] = a1;
        *(bf16x8*)&my[n15][64 + q * 8] = a2;
        *(bf16x8*)&my[n15][96 + q * 8] = a3;
        *(unsigned*)&my[16][lane * 2]  = xw;

        // next item's loads in flight (r, x now dead)
        if (next < ITEMS) ISSUE(next);

        // MFMA straight from registers -- no LDS, no fence on this path
        f32x4 acc[4], aRS = (f32x4){0.f, 0.f, 0.f, 0.f};
        #pragma unroll
        for (int c4 = 0; c4 < 4; ++c4) acc[c4] = (f32x4){0.f, 0.f, 0.f, 0.f};
        KSTEP(a0, 0); KSTEP(a1, 1); KSTEP(a2, 2); KSTEP(a3, 3);

        lds_fence();   // epilogue-copy writes visible (completed under MFMA)

        // epilogue: C/D row = q*4+reg, col = n15 (per 16-tile)
        const long r0 = (long)(item >> 1) * 16;
        #pragma unroll
        for (int reg = 0; reg < 4; ++reg) {
            const int row = q * 4 + reg;
            const float rs = aRS[reg];
            const long s = r0 + row;
            const bool has = (s < S_LEN - 1);
            #pragma unroll
            for (int c4 = 0; c4 < 4; ++c4) {
                const float z = acc[c4][reg];
                const float sp = fmaxf(z, 0.f) + __logf(1.0f + __expf(-fabsf(z)));
                const float o = sp * rs;
                if (has) {
                    const int col = half * 64 + c4 * 16 + n15;
                    const float d = o - bf2f(my[row + 1][col]);
                    lsum = fmaf(d, d, lsum);
                }
            }
        }

        lds_fence();   // epilogue reads done before next iteration's writes
        item = next;
    }

    const float wsum = wave_reduce(lsum);
    if ((tid & 63) == 0) sRed[w] = wsum;
    __syncthreads();
    if (tid == 0) {
        float t = 0.f;
        #pragma unroll
        for (int w2 = 0; w2 < 4; ++w2) t += sRed[w2];
        atomicAdd(&out[0], t * inv_denom);
    }
}

extern "C" void kernel_launch(void* const* d_in, const int* in_sizes, int n_in,
                              void* d_out, int out_size, void* d_ws, size_t ws_size,
                              hipStream_t stream) {
    const float* In = (const float*)d_in[0];
    const float* WQ = (const float*)d_in[1];
    const float* WK = (const float*)d_in[2];
    float* out = (float*)d_out;
    unsigned short* fragB = (unsigned short*)d_ws;          // 32 KB
    float* wsP = (float*)((char*)d_ws + 32 * 1024);         // 128 floats: l1 partials

    mk_kernel<<<128, 128, 0, stream>>>(WQ, WK, fragB, wsP, out);
    const float inv = (float)(1.0 / ((double)(S_LEN - 1) * (double)N));
    main_kernel<<<GRID, TPB, 0, stream>>>(In, fragB, wsP, out, inv);
}